// Round 9
// baseline (82.941 us; speedup 1.0000x reference)
//
#include <hip/hip_runtime.h>
#include <hip/hip_bf16.h>

// RoIAlign forward, torchvision semantics (aligned=false), fp32 in/out.
// N=2, C=256, H=200, W=200, K=1000 rois, pooled 7x7, sampling_ratio=2.
// Strategy: NCHW f32 -> NHWC bf16 staging map (41 MB), device counting-sort
// of rois by (batch, y-center), then persistent work-stealing blocks pulling
// (roi, channel-half) units in sorted order -> concurrently-running blocks
// share a narrow y-window of the map (L2-resident per XCD, shorter miss
// latency through the per-CU miss-path slots that cap gather throughput).
// Inner loop = R4's plain form (batching/sched_barrier proven harmful R5-R8).
constexpr int Nn = 2, Cc = 256, Hh = 200, Ww = 200, Kk = 1000;
constexpr int PH = 7, PW = 7, SR = 2;
constexpr float SCALE = 0.25f;
constexpr int HWsz = Hh * Ww;
constexpr unsigned NUNITS = 2 * Kk;  // (roi, half) pairs

// ---------------------------------------------------------------------------
// NCHW fp32 -> NHWC bf16 (RTNE). 64x64 LDS tiles, coalesced both sides.
// ---------------------------------------------------------------------------
__global__ __launch_bounds__(256) void transpose_to_nhwc_bf16(
    const float* __restrict__ in, __hip_bfloat16* __restrict__ out) {
  __shared__ float tile[64][65];
  const int hw0 = blockIdx.x * 64;
  const int c0  = blockIdx.y * 64;
  const int b   = blockIdx.z;
  const int lane = threadIdx.x & 63;
  const int row  = threadIdx.x >> 6;  // 0..3

#pragma unroll
  for (int i = 0; i < 16; ++i) {
    const int cc = row + i * 4;
    tile[cc][lane] = in[(size_t)(b * Cc + c0 + cc) * HWsz + hw0 + lane];
  }
  __syncthreads();
#pragma unroll
  for (int i = 0; i < 16; ++i) {
    const int hh = row + i * 4;
    out[((size_t)b * HWsz + hw0 + hh) * Cc + c0 + lane] =
        __float2bfloat16(tile[lane][hh]);
  }
}

// ---------------------------------------------------------------------------
// Counting sort of rois by (batch, y-center bucket). 1 block, 400 buckets.
// Output `order[K]`: roi indices grouped by bucket. Per-roi OUTPUT does not
// depend on processing order, so intra-bucket nondeterminism is harmless.
// ---------------------------------------------------------------------------
__global__ __launch_bounds__(1024) void sort_rois(
    const float* __restrict__ rois, unsigned* __restrict__ order) {
  __shared__ unsigned hist[400];
  __shared__ unsigned base[400];
  const int tid = (int)threadIdx.x;
  if (tid < 400) hist[tid] = 0;
  __syncthreads();
  for (int k = tid; k < Kk; k += 1024) {
    const float* r = rois + k * 5;
    int yc = (int)(0.5f * (r[2] + r[4]) * SCALE);
    yc = yc < 0 ? 0 : (yc > 199 ? 199 : yc);
    atomicAdd(&hist[(int)r[0] * 200 + yc], 1u);
  }
  __syncthreads();
  if (tid == 0) {
    unsigned s = 0;
    for (int i = 0; i < 400; ++i) { base[i] = s; s += hist[i]; }
  }
  __syncthreads();
  for (int k = tid; k < Kk; k += 1024) {
    const float* r = rois + k * 5;
    int yc = (int)(0.5f * (r[2] + r[4]) * SCALE);
    yc = yc < 0 ? 0 : (yc > 199 ? 199 : yc);
    const unsigned pos = atomicAdd(&base[(int)r[0] * 200 + yc], 1u);
    order[pos] = (unsigned)k;
  }
}

// Skewed LDS index: writer lanes land on bank stride 17 (coprime with 32)
// -> conflict-free writes; reads quasi-linear.
__device__ __forceinline__ int sidx(int c, int p) {
  return c * 49 + p + 13 * (c >> 2);
}

// ---------------------------------------------------------------------------
// Persistent work-stealing RoI align on NHWC bf16, sorted unit order.
// Block = 448 threads (7 waves); unit u -> roi order[u>>1], half u&1.
//   wave = pooled row ph; ixl = lane>>5 (x-sample column); cq = lane&31
//   (channel quad, 8B ushort4 loads -> 2x256B fully-coalesced segments).
// ---------------------------------------------------------------------------
__global__ __launch_bounds__(448, 4) void roi_align_ws(
    const ushort* __restrict__ feat, const float* __restrict__ rois,
    const unsigned* __restrict__ order, float* __restrict__ out,
    unsigned* __restrict__ counter) {
  __shared__ float stage[6704];  // 128ch x 49, skewed (max idx 6674)
  __shared__ unsigned s_unit;

  const int tid  = (int)threadIdx.x;
  const int ph   = tid >> 6;        // 0..6
  const int lane = tid & 63;
  const int ixl  = lane >> 5;       // sample column parity
  const int cq   = lane & 31;       // channel quad in half

  auto bf2f = [](ushort u) -> float {
    return __uint_as_float((unsigned)u << 16);
  };
  const float x_off = ((float)ixl + 0.5f) * 0.5f;  // per-lane sample offset

  for (;;) {
    if (tid == 0) s_unit = atomicAdd(counter, 1u);
    __syncthreads();  // A: s_unit visible; prev epilogue stage-reads done
    const unsigned unit = s_unit;
    if (unit >= NUNITS) return;  // block-uniform

    const int k    = (int)order[unit >> 1];
    const int half = (int)(unit & 1);

    const float* r = rois + k * 5;
    const int b = (int)r[0];
    const float x1 = r[1] * SCALE;
    const float y1 = r[2] * SCALE;
    const float x2 = r[3] * SCALE;
    const float y2 = r[4] * SCALE;
    const float bin_w = fmaxf(x2 - x1, 1.0f) * (1.0f / PW);
    const float bin_h = fmaxf(y2 - y1, 1.0f) * (1.0f / PH);

    // ushort4 view; per-(y,x) stride is 64 quads; this lane's channel quad.
    const ushort4* fb =
        (const ushort4*)(feat + (size_t)b * HWsz * Cc) + half * 32 + cq;

    float4 acc[PW];
#pragma unroll
    for (int i = 0; i < PW; ++i) acc[i] = make_float4(0.f, 0.f, 0.f, 0.f);

#pragma unroll
    for (int iy = 0; iy < SR; ++iy) {
      const float y  = y1 + ((float)ph + ((float)iy + 0.5f) * 0.5f) * bin_h;
      const bool vy  = (y >= -1.0f) && (y <= (float)Hh);
      const float cy = fmaxf(y, 0.0f);
      int yl = (int)cy;  // cy >= 0: trunc == floor
      int yh;
      float fy;
      if (yl >= Hh - 1) { yl = Hh - 1; yh = Hh - 1; fy = 0.0f; }
      else              { yh = yl + 1; fy = cy - (float)yl; }
      float wyl = 1.0f - fy, wyh = fy;
      if (!vy) { wyl = 0.0f; wyh = 0.0f; }
      const int ylb = yl * Ww, yhb = yh * Ww;

#pragma unroll
      for (int pw = 0; pw < PW; ++pw) {
        const float x  = x1 + ((float)pw + x_off) * bin_w;  // per-lane
        const bool vx  = (x >= -1.0f) && (x <= (float)Ww);
        const float cx = fmaxf(x, 0.0f);
        int xl = (int)cx;
        int xh;
        float fx;
        if (xl >= Ww - 1) { xl = Ww - 1; xh = Ww - 1; fx = 0.0f; }
        else              { xh = xl + 1; fx = cx - (float)xl; }
        float wxl = 1.0f - fx, wxh = fx;
        if (!vx) { wxl = 0.0f; wxh = 0.0f; }

        const float w00 = wyl * wxl, w01 = wyl * wxh;
        const float w10 = wyh * wxl, w11 = wyh * wxh;

        const ushort4 v00 = fb[(ylb + xl) * 64];
        const ushort4 v01 = fb[(ylb + xh) * 64];
        const ushort4 v10 = fb[(yhb + xl) * 64];
        const ushort4 v11 = fb[(yhb + xh) * 64];

        acc[pw].x = fmaf(w00, bf2f(v00.x), fmaf(w01, bf2f(v01.x),
                    fmaf(w10, bf2f(v10.x), fmaf(w11, bf2f(v11.x), acc[pw].x))));
        acc[pw].y = fmaf(w00, bf2f(v00.y), fmaf(w01, bf2f(v01.y),
                    fmaf(w10, bf2f(v10.y), fmaf(w11, bf2f(v11.y), acc[pw].y))));
        acc[pw].z = fmaf(w00, bf2f(v00.z), fmaf(w01, bf2f(v01.z),
                    fmaf(w10, bf2f(v10.z), fmaf(w11, bf2f(v11.z), acc[pw].z))));
        acc[pw].w = fmaf(w00, bf2f(v00.w), fmaf(w01, bf2f(v01.w),
                    fmaf(w10, bf2f(v10.w), fmaf(w11, bf2f(v11.w), acc[pw].w))));
      }
    }

    // Fold the two x-sample columns: lane L <-> lane L^32.
#pragma unroll
    for (int pw = 0; pw < PW; ++pw) {
      acc[pw].x += __shfl_xor(acc[pw].x, 32);
      acc[pw].y += __shfl_xor(acc[pw].y, 32);
      acc[pw].z += __shfl_xor(acc[pw].z, 32);
      acc[pw].w += __shfl_xor(acc[pw].w, 32);
    }

    const float inv = 1.0f / (SR * SR);
    // Stage 128x49 output tile in LDS (lanes 0-31 hold full sums).
    if (lane < 32) {
      const int c0 = cq * 4;
      const int p = ph * PW;
#pragma unroll
      for (int pw = 0; pw < PW; ++pw) {
        stage[sidx(c0 + 0, p + pw)] = acc[pw].x * inv;
        stage[sidx(c0 + 1, p + pw)] = acc[pw].y * inv;
        stage[sidx(c0 + 2, p + pw)] = acc[pw].z * inv;
        stage[sidx(c0 + 3, p + pw)] = acc[pw].w * inv;
      }
    }
    __syncthreads();  // B: stage ready

    const size_t obase =
        (size_t)k * (Cc * PH * PW) + (size_t)half * (128 * PH * PW);
#pragma unroll
    for (int i = 0; i < 14; ++i) {  // 128*49 = 6272 = 448*14
      const int idx = i * 448 + tid;
      const int c = idx / 49, p = idx - c * 49;
      // Non-temporal: don't let the output evict the bf16 map in L2/L3.
      __builtin_nontemporal_store(stage[sidx(c, p)], &out[obase + idx]);
    }
    // Loop: barrier A separates these stage reads from the next writes.
  }
}

extern "C" void kernel_launch(void* const* d_in, const int* in_sizes, int n_in,
                              void* d_out, int out_size, void* d_ws, size_t ws_size,
                              hipStream_t stream) {
  const float* inp  = (const float*)d_in[0];   // (2,256,200,200) fp32
  const float* rois = (const float*)d_in[1];   // (1000,5) fp32
  float* out = (float*)d_out;                  // (1000,256,7,7) fp32

  __hip_bfloat16* nhwc = (__hip_bfloat16*)d_ws;                // 41 MB
  unsigned* counter = (unsigned*)((char*)d_ws + (48u << 20));  // 48MB offset
  unsigned* order   = counter + 64;                            // 4KB

  transpose_to_nhwc_bf16<<<dim3(HWsz / 64, Cc / 64, Nn), 256, 0, stream>>>(inp, nhwc);
  sort_rois<<<dim3(1), 1024, 0, stream>>>(rois, order);
  hipMemsetAsync(counter, 0, sizeof(unsigned), stream);
  roi_align_ws<<<dim3(1024), 448, 0, stream>>>((const ushort*)nhwc, rois, order, out, counter);
}

// Round 10
// 67.168 us; speedup vs baseline: 1.2348x; 1.2348x over previous
//
#include <hip/hip_runtime.h>
#include <hip/hip_bf16.h>

// RoIAlign forward, torchvision semantics (aligned=false), fp32 in/out.
// N=2, C=256, H=200, W=200, K=1000 rois, pooled 7x7, sampling_ratio=2.
// Model (R1-R9): dur ~= hbm_bytes / ~2.8 TB/s in every round -> HBM-bound on
// scattered 256B reads, NOT occupancy/MLP (R7/R8 falsified those). R10:
// concentrate each XCD on a contiguous y-band of (batch,y)-sorted rois via
// chunked blockIdx swizzle -> per-XCD L2 serves repeat touches, map lines
// stream from L3/HBM ~once in y-order. No stealing (R8: no benefit).
constexpr int Nn = 2, Cc = 256, Hh = 200, Ww = 200, Kk = 1000;
constexpr int PH = 7, PW = 7, SR = 2;
constexpr float SCALE = 0.25f;
constexpr int HWsz = Hh * Ww;
constexpr int NXCD = 8;
constexpr unsigned NUNITS = 2 * Kk;             // (roi, half) pairs
constexpr unsigned CHUNK = NUNITS / NXCD;       // 250

// ---------------------------------------------------------------------------
// NCHW fp32 -> NHWC bf16 (RTNE). 64x64 LDS tiles, coalesced both sides.
// ---------------------------------------------------------------------------
__global__ __launch_bounds__(256) void transpose_to_nhwc_bf16(
    const float* __restrict__ in, __hip_bfloat16* __restrict__ out) {
  __shared__ float tile[64][65];
  const int hw0 = blockIdx.x * 64;
  const int c0  = blockIdx.y * 64;
  const int b   = blockIdx.z;
  const int lane = threadIdx.x & 63;
  const int row  = threadIdx.x >> 6;  // 0..3

#pragma unroll
  for (int i = 0; i < 16; ++i) {
    const int cc = row + i * 4;
    tile[cc][lane] = in[(size_t)(b * Cc + c0 + cc) * HWsz + hw0 + lane];
  }
  __syncthreads();
#pragma unroll
  for (int i = 0; i < 16; ++i) {
    const int hh = row + i * 4;
    out[((size_t)b * HWsz + hw0 + hh) * Cc + c0 + lane] =
        __float2bfloat16(tile[lane][hh]);
  }
}

// ---------------------------------------------------------------------------
// Counting sort of rois by (batch, y-center bucket). 1 block, 400 buckets.
// Per-roi output location is fixed by roi index, so any intra-bucket order
// is correct; only performance depends on it.
// ---------------------------------------------------------------------------
__global__ __launch_bounds__(1024) void sort_rois(
    const float* __restrict__ rois, unsigned* __restrict__ order) {
  __shared__ unsigned hist[400];
  __shared__ unsigned base[400];
  const int tid = (int)threadIdx.x;
  if (tid < 400) hist[tid] = 0;
  __syncthreads();
  for (int k = tid; k < Kk; k += 1024) {
    const float* r = rois + k * 5;
    int yc = (int)(0.5f * (r[2] + r[4]) * SCALE);
    yc = yc < 0 ? 0 : (yc > 199 ? 199 : yc);
    atomicAdd(&hist[(int)r[0] * 200 + yc], 1u);
  }
  __syncthreads();
  if (tid == 0) {
    unsigned s = 0;
    for (int i = 0; i < 400; ++i) { base[i] = s; s += hist[i]; }
  }
  __syncthreads();
  for (int k = tid; k < Kk; k += 1024) {
    const float* r = rois + k * 5;
    int yc = (int)(0.5f * (r[2] + r[4]) * SCALE);
    yc = yc < 0 ? 0 : (yc > 199 ? 199 : yc);
    const unsigned pos = atomicAdd(&base[(int)r[0] * 200 + yc], 1u);
    order[pos] = (unsigned)k;
  }
}

// Skewed LDS index: writer lanes land on bank stride 17 (coprime with 32)
// -> conflict-free writes; reads quasi-linear.
__device__ __forceinline__ int sidx(int c, int p) {
  return c * 49 + p + 13 * (c >> 2);
}

// ---------------------------------------------------------------------------
// RoI align on NHWC bf16, XCD-chunked over sorted units.
// Block bid -> xcd = bid%8 (HW round-robin), pos = bid/8;
// unit = xcd*CHUNK + pos  => XCD x owns sorted range [x*250, (x+1)*250).
// Block = 448 threads (7 waves); unit -> (roi = order[u>>1], half = u&1).
//   wave = pooled row ph; ixl = lane>>5 (x-sample column); cq = lane&31
//   (channel quad, 8B ushort4 loads -> 2x256B fully-coalesced segments).
// ---------------------------------------------------------------------------
__global__ __launch_bounds__(448, 4) void roi_align_xcd(
    const ushort* __restrict__ feat, const float* __restrict__ rois,
    const unsigned* __restrict__ order, float* __restrict__ out) {
  __shared__ float stage[6704];  // 128ch x 49, skewed (max idx 6674)

  const unsigned bid = blockIdx.x;
  const unsigned unit = (bid % NXCD) * CHUNK + bid / NXCD;

  const int tid  = (int)threadIdx.x;
  const int ph   = tid >> 6;        // 0..6
  const int lane = tid & 63;
  const int ixl  = lane >> 5;       // sample column parity
  const int cq   = lane & 31;       // channel quad in half

  const int k    = (int)order[unit >> 1];
  const int half = (int)(unit & 1);

  const float* r = rois + k * 5;
  const int b = (int)r[0];
  const float x1 = r[1] * SCALE;
  const float y1 = r[2] * SCALE;
  const float x2 = r[3] * SCALE;
  const float y2 = r[4] * SCALE;
  const float bin_w = fmaxf(x2 - x1, 1.0f) * (1.0f / PW);
  const float bin_h = fmaxf(y2 - y1, 1.0f) * (1.0f / PH);

  // ushort4 view; per-(y,x) stride is 64 quads; this lane's channel quad.
  const ushort4* fb =
      (const ushort4*)(feat + (size_t)b * HWsz * Cc) + half * 32 + cq;

  float4 acc[PW];
#pragma unroll
  for (int i = 0; i < PW; ++i) acc[i] = make_float4(0.f, 0.f, 0.f, 0.f);

  auto bf2f = [](ushort u) -> float {
    return __uint_as_float((unsigned)u << 16);
  };
  const float x_off = ((float)ixl + 0.5f) * 0.5f;  // per-lane sample offset

#pragma unroll
  for (int iy = 0; iy < SR; ++iy) {
    const float y  = y1 + ((float)ph + ((float)iy + 0.5f) * 0.5f) * bin_h;
    const bool vy  = (y >= -1.0f) && (y <= (float)Hh);
    const float cy = fmaxf(y, 0.0f);
    int yl = (int)cy;  // cy >= 0: trunc == floor
    int yh;
    float fy;
    if (yl >= Hh - 1) { yl = Hh - 1; yh = Hh - 1; fy = 0.0f; }
    else              { yh = yl + 1; fy = cy - (float)yl; }
    float wyl = 1.0f - fy, wyh = fy;
    if (!vy) { wyl = 0.0f; wyh = 0.0f; }
    const int ylb = yl * Ww, yhb = yh * Ww;

#pragma unroll
    for (int pw = 0; pw < PW; ++pw) {
      const float x  = x1 + ((float)pw + x_off) * bin_w;  // per-lane
      const bool vx  = (x >= -1.0f) && (x <= (float)Ww);
      const float cx = fmaxf(x, 0.0f);
      int xl = (int)cx;
      int xh;
      float fx;
      if (xl >= Ww - 1) { xl = Ww - 1; xh = Ww - 1; fx = 0.0f; }
      else              { xh = xl + 1; fx = cx - (float)xl; }
      float wxl = 1.0f - fx, wxh = fx;
      if (!vx) { wxl = 0.0f; wxh = 0.0f; }

      const float w00 = wyl * wxl, w01 = wyl * wxh;
      const float w10 = wyh * wxl, w11 = wyh * wxh;

      const ushort4 v00 = fb[(ylb + xl) * 64];
      const ushort4 v01 = fb[(ylb + xh) * 64];
      const ushort4 v10 = fb[(yhb + xl) * 64];
      const ushort4 v11 = fb[(yhb + xh) * 64];

      acc[pw].x = fmaf(w00, bf2f(v00.x), fmaf(w01, bf2f(v01.x),
                  fmaf(w10, bf2f(v10.x), fmaf(w11, bf2f(v11.x), acc[pw].x))));
      acc[pw].y = fmaf(w00, bf2f(v00.y), fmaf(w01, bf2f(v01.y),
                  fmaf(w10, bf2f(v10.y), fmaf(w11, bf2f(v11.y), acc[pw].y))));
      acc[pw].z = fmaf(w00, bf2f(v00.z), fmaf(w01, bf2f(v01.z),
                  fmaf(w10, bf2f(v10.z), fmaf(w11, bf2f(v11.z), acc[pw].z))));
      acc[pw].w = fmaf(w00, bf2f(v00.w), fmaf(w01, bf2f(v01.w),
                  fmaf(w10, bf2f(v10.w), fmaf(w11, bf2f(v11.w), acc[pw].w))));
    }
  }

  // Fold the two x-sample columns: lane L <-> lane L^32.
#pragma unroll
  for (int pw = 0; pw < PW; ++pw) {
    acc[pw].x += __shfl_xor(acc[pw].x, 32);
    acc[pw].y += __shfl_xor(acc[pw].y, 32);
    acc[pw].z += __shfl_xor(acc[pw].z, 32);
    acc[pw].w += __shfl_xor(acc[pw].w, 32);
  }

  const float inv = 1.0f / (SR * SR);
  // Stage 128x49 output tile in LDS (lanes 0-31 hold full sums).
  if (lane < 32) {
    const int c0 = cq * 4;
    const int p = ph * PW;
#pragma unroll
    for (int pw = 0; pw < PW; ++pw) {
      stage[sidx(c0 + 0, p + pw)] = acc[pw].x * inv;
      stage[sidx(c0 + 1, p + pw)] = acc[pw].y * inv;
      stage[sidx(c0 + 2, p + pw)] = acc[pw].z * inv;
      stage[sidx(c0 + 3, p + pw)] = acc[pw].w * inv;
    }
  }
  __syncthreads();

  const size_t obase =
      (size_t)k * (Cc * PH * PW) + (size_t)half * (128 * PH * PW);
#pragma unroll
  for (int i = 0; i < 14; ++i) {  // 128*49 = 6272 = 448*14
    const int idx = i * 448 + tid;
    const int c = idx / 49, p = idx - c * 49;
    // Non-temporal: don't let the output evict the bf16 map in L2/L3.
    __builtin_nontemporal_store(stage[sidx(c, p)], &out[obase + idx]);
  }
}

extern "C" void kernel_launch(void* const* d_in, const int* in_sizes, int n_in,
                              void* d_out, int out_size, void* d_ws, size_t ws_size,
                              hipStream_t stream) {
  const float* inp  = (const float*)d_in[0];   // (2,256,200,200) fp32
  const float* rois = (const float*)d_in[1];   // (1000,5) fp32
  float* out = (float*)d_out;                  // (1000,256,7,7) fp32

  __hip_bfloat16* nhwc = (__hip_bfloat16*)d_ws;                // 41 MB
  unsigned* order = (unsigned*)((char*)d_ws + (48u << 20));    // 4KB @48MB

  transpose_to_nhwc_bf16<<<dim3(HWsz / 64, Cc / 64, Nn), 256, 0, stream>>>(inp, nhwc);
  sort_rois<<<dim3(1), 1024, 0, stream>>>(rois, order);
  roi_align_xcd<<<dim3(NUNITS), 448, 0, stream>>>((const ushort*)nhwc, rois, order, out);
}

// Round 11
// 65.160 us; speedup vs baseline: 1.2729x; 1.0308x over previous
//
#include <hip/hip_runtime.h>
#include <hip/hip_bf16.h>

// RoIAlign forward, torchvision semantics (aligned=false), fp32 in/out.
// N=2, C=256, H=200, W=200, K=1000 rois, pooled 7x7, sampling_ratio=2.
// Model (R1-R10): gather-request-path bound (~8 TB/s delivered), with dur
// tracking L2-miss traffic (FETCH). R11: Morton (2D-local) roi order so each
// map slot's touches fit inside one XCD's live block window -> one fetch
// epoch per slot (FETCH -> ~map size).
constexpr int Nn = 2, Cc = 256, Hh = 200, Ww = 200, Kk = 1000;
constexpr int PH = 7, PW = 7, SR = 2;
constexpr float SCALE = 0.25f;
constexpr int HWsz = Hh * Ww;
constexpr int NXCD = 8;
constexpr unsigned NUNITS = 2 * Kk;             // (roi, half) pairs
constexpr unsigned CHUNK = NUNITS / NXCD;       // 250

// ---------------------------------------------------------------------------
// NCHW fp32 -> NHWC bf16 (RTNE). 64x64 LDS tiles, coalesced both sides.
// ---------------------------------------------------------------------------
__global__ __launch_bounds__(256) void transpose_to_nhwc_bf16(
    const float* __restrict__ in, __hip_bfloat16* __restrict__ out) {
  __shared__ float tile[64][65];
  const int hw0 = blockIdx.x * 64;
  const int c0  = blockIdx.y * 64;
  const int b   = blockIdx.z;
  const int lane = threadIdx.x & 63;
  const int row  = threadIdx.x >> 6;  // 0..3

#pragma unroll
  for (int i = 0; i < 16; ++i) {
    const int cc = row + i * 4;
    tile[cc][lane] = in[(size_t)(b * Cc + c0 + cc) * HWsz + hw0 + lane];
  }
  __syncthreads();
#pragma unroll
  for (int i = 0; i < 16; ++i) {
    const int hh = row + i * 4;
    out[((size_t)b * HWsz + hw0 + hh) * Cc + c0 + lane] =
        __float2bfloat16(tile[lane][hh]);
  }
}

// ---------------------------------------------------------------------------
// Morton-order counting sort of rois by (batch, morton(yc/8, xc/8)).
// 2048 buckets; 1000 rois -> single-pass with 1024 threads; Hillis-Steele
// scan over the histogram. Per-roi output location is fixed by roi index,
// so intra-bucket order nondeterminism is harmless.
// ---------------------------------------------------------------------------
__global__ __launch_bounds__(1024) void sort_rois(
    const float* __restrict__ rois, unsigned* __restrict__ order) {
  __shared__ unsigned A[2048], B[2048];
  const int tid = (int)threadIdx.x;
  A[tid] = 0; A[tid + 1024] = 0;
  __syncthreads();

  unsigned kk = 0;
  const bool act = tid < Kk;
  if (act) {
    const float* r = rois + tid * 5;
    int yc = (int)(0.5f * (r[2] + r[4]) * SCALE);
    int xc = (int)(0.5f * (r[1] + r[3]) * SCALE);
    yc = yc < 0 ? 0 : (yc > 199 ? 199 : yc);
    xc = xc < 0 ? 0 : (xc > 199 ? 199 : xc);
    const unsigned ty = (unsigned)yc >> 3, tx = (unsigned)xc >> 3;  // 0..24
    unsigned m = 0;
#pragma unroll
    for (int i = 0; i < 5; ++i)
      m |= (((ty >> i) & 1u) << (2 * i + 1)) | (((tx >> i) & 1u) << (2 * i));
    kk = (unsigned)r[0] * 1024u + m;
    atomicAdd(&A[kk], 1u);
  }
  __syncthreads();

  // Inclusive scan over 2048 (11 doubling steps, ping-pong A<->B).
  unsigned* src = A;
  unsigned* dst = B;
  for (int d = 1; d < 2048; d <<= 1) {
    for (int j = tid; j < 2048; j += 1024) {
      unsigned v = src[j];
      if (j >= d) v += src[j - d];
      dst[j] = v;
    }
    __syncthreads();
    unsigned* t = src; src = dst; dst = t;
  }
  // Exclusive base into dst.
  for (int j = tid; j < 2048; j += 1024) dst[j] = j ? src[j - 1] : 0u;
  __syncthreads();

  if (act) {
    const unsigned pos = atomicAdd(&dst[kk], 1u);
    order[pos] = (unsigned)tid;
  }
}

// Skewed LDS index: writer lanes land on bank stride 17 (coprime with 32)
// -> conflict-free writes; reads quasi-linear.
__device__ __forceinline__ int sidx(int c, int p) {
  return c * 49 + p + 13 * (c >> 2);
}

// ---------------------------------------------------------------------------
// RoI align on NHWC bf16, XCD-chunked over Morton-sorted units.
// Block bid -> xcd = bid%8 (HW round-robin), pos = bid/8;
// unit = xcd*CHUNK + pos  => XCD x owns sorted range [x*250, (x+1)*250).
// Block = 448 threads (7 waves); unit -> (roi = order[u>>1], half = u&1).
//   wave = pooled row ph; ixl = lane>>5 (x-sample column); cq = lane&31
//   (channel quad, 8B ushort4 loads -> 2x256B fully-coalesced segments).
// ---------------------------------------------------------------------------
__global__ __launch_bounds__(448, 4) void roi_align_xcd(
    const ushort* __restrict__ feat, const float* __restrict__ rois,
    const unsigned* __restrict__ order, float* __restrict__ out) {
  __shared__ float stage[6704];  // 128ch x 49, skewed (max idx 6674)

  const unsigned bid = blockIdx.x;
  const unsigned unit = (bid % NXCD) * CHUNK + bid / NXCD;

  const int tid  = (int)threadIdx.x;
  const int ph   = tid >> 6;        // 0..6
  const int lane = tid & 63;
  const int ixl  = lane >> 5;       // sample column parity
  const int cq   = lane & 31;       // channel quad in half

  const int k    = (int)order[unit >> 1];
  const int half = (int)(unit & 1);

  const float* r = rois + k * 5;
  const int b = (int)r[0];
  const float x1 = r[1] * SCALE;
  const float y1 = r[2] * SCALE;
  const float x2 = r[3] * SCALE;
  const float y2 = r[4] * SCALE;
  const float bin_w = fmaxf(x2 - x1, 1.0f) * (1.0f / PW);
  const float bin_h = fmaxf(y2 - y1, 1.0f) * (1.0f / PH);

  // ushort4 view; per-(y,x) stride is 64 quads; this lane's channel quad.
  const ushort4* fb =
      (const ushort4*)(feat + (size_t)b * HWsz * Cc) + half * 32 + cq;

  float4 acc[PW];
#pragma unroll
  for (int i = 0; i < PW; ++i) acc[i] = make_float4(0.f, 0.f, 0.f, 0.f);

  auto bf2f = [](ushort u) -> float {
    return __uint_as_float((unsigned)u << 16);
  };
  const float x_off = ((float)ixl + 0.5f) * 0.5f;  // per-lane sample offset

#pragma unroll
  for (int iy = 0; iy < SR; ++iy) {
    const float y  = y1 + ((float)ph + ((float)iy + 0.5f) * 0.5f) * bin_h;
    const bool vy  = (y >= -1.0f) && (y <= (float)Hh);
    const float cy = fmaxf(y, 0.0f);
    int yl = (int)cy;  // cy >= 0: trunc == floor
    int yh;
    float fy;
    if (yl >= Hh - 1) { yl = Hh - 1; yh = Hh - 1; fy = 0.0f; }
    else              { yh = yl + 1; fy = cy - (float)yl; }
    float wyl = 1.0f - fy, wyh = fy;
    if (!vy) { wyl = 0.0f; wyh = 0.0f; }
    const int ylb = yl * Ww, yhb = yh * Ww;

#pragma unroll
    for (int pw = 0; pw < PW; ++pw) {
      const float x  = x1 + ((float)pw + x_off) * bin_w;  // per-lane
      const bool vx  = (x >= -1.0f) && (x <= (float)Ww);
      const float cx = fmaxf(x, 0.0f);
      int xl = (int)cx;
      int xh;
      float fx;
      if (xl >= Ww - 1) { xl = Ww - 1; xh = Ww - 1; fx = 0.0f; }
      else              { xh = xl + 1; fx = cx - (float)xl; }
      float wxl = 1.0f - fx, wxh = fx;
      if (!vx) { wxl = 0.0f; wxh = 0.0f; }

      const float w00 = wyl * wxl, w01 = wyl * wxh;
      const float w10 = wyh * wxl, w11 = wyh * wxh;

      const ushort4 v00 = fb[(ylb + xl) * 64];
      const ushort4 v01 = fb[(ylb + xh) * 64];
      const ushort4 v10 = fb[(yhb + xl) * 64];
      const ushort4 v11 = fb[(yhb + xh) * 64];

      acc[pw].x = fmaf(w00, bf2f(v00.x), fmaf(w01, bf2f(v01.x),
                  fmaf(w10, bf2f(v10.x), fmaf(w11, bf2f(v11.x), acc[pw].x))));
      acc[pw].y = fmaf(w00, bf2f(v00.y), fmaf(w01, bf2f(v01.y),
                  fmaf(w10, bf2f(v10.y), fmaf(w11, bf2f(v11.y), acc[pw].y))));
      acc[pw].z = fmaf(w00, bf2f(v00.z), fmaf(w01, bf2f(v01.z),
                  fmaf(w10, bf2f(v10.z), fmaf(w11, bf2f(v11.z), acc[pw].z))));
      acc[pw].w = fmaf(w00, bf2f(v00.w), fmaf(w01, bf2f(v01.w),
                  fmaf(w10, bf2f(v10.w), fmaf(w11, bf2f(v11.w), acc[pw].w))));
    }
  }

  // Fold the two x-sample columns: lane L <-> lane L^32.
#pragma unroll
  for (int pw = 0; pw < PW; ++pw) {
    acc[pw].x += __shfl_xor(acc[pw].x, 32);
    acc[pw].y += __shfl_xor(acc[pw].y, 32);
    acc[pw].z += __shfl_xor(acc[pw].z, 32);
    acc[pw].w += __shfl_xor(acc[pw].w, 32);
  }

  const float inv = 1.0f / (SR * SR);
  // Stage 128x49 output tile in LDS (lanes 0-31 hold full sums).
  if (lane < 32) {
    const int c0 = cq * 4;
    const int p = ph * PW;
#pragma unroll
    for (int pw = 0; pw < PW; ++pw) {
      stage[sidx(c0 + 0, p + pw)] = acc[pw].x * inv;
      stage[sidx(c0 + 1, p + pw)] = acc[pw].y * inv;
      stage[sidx(c0 + 2, p + pw)] = acc[pw].z * inv;
      stage[sidx(c0 + 3, p + pw)] = acc[pw].w * inv;
    }
  }
  __syncthreads();

  const size_t obase =
      (size_t)k * (Cc * PH * PW) + (size_t)half * (128 * PH * PW);
#pragma unroll
  for (int i = 0; i < 14; ++i) {  // 128*49 = 6272 = 448*14
    const int idx = i * 448 + tid;
    const int c = idx / 49, p = idx - c * 49;
    // Non-temporal: don't let the output evict the bf16 map in L2/L3.
    __builtin_nontemporal_store(stage[sidx(c, p)], &out[obase + idx]);
  }
}

extern "C" void kernel_launch(void* const* d_in, const int* in_sizes, int n_in,
                              void* d_out, int out_size, void* d_ws, size_t ws_size,
                              hipStream_t stream) {
  const float* inp  = (const float*)d_in[0];   // (2,256,200,200) fp32
  const float* rois = (const float*)d_in[1];   // (1000,5) fp32
  float* out = (float*)d_out;                  // (1000,256,7,7) fp32

  __hip_bfloat16* nhwc = (__hip_bfloat16*)d_ws;                // 41 MB
  unsigned* order = (unsigned*)((char*)d_ws + (48u << 20));    // 4KB @48MB

  transpose_to_nhwc_bf16<<<dim3(HWsz / 64, Cc / 64, Nn), 256, 0, stream>>>(inp, nhwc);
  sort_rois<<<dim3(1), 1024, 0, stream>>>(rois, order);
  roi_align_xcd<<<dim3(NUNITS), 448, 0, stream>>>((const ushort*)nhwc, rois, order, out);
}